// Round 1
// baseline (179.865 us; speedup 1.0000x reference)
//
#include <hip/hip_runtime.h>

// SWD18: per-feature cyclic window-of-5 sort (reduction verified absmax=0, R1-R7):
// for column i, sort rows {5m + (i%5) + j mod L, j=0..4} ascending, in place.
// q, k are dead inputs.
//
// R8 (prev session): 30 upfront scalar loads per thread (rows [R0-5, R0+25)),
// 4 groups of verified A/B window mux + 9-comparator sorts, 20 coalesced NT
// stores. Traffic 96 MB read + 64 MB write = 160 MB -> ~25 us kernel slice.
//
// R9 (this round): T1 bijective XCD-chunk swizzle, body UNCHANGED.
// The 10 halo rows per strip (1.5x read amp) are exactly the rows the
// adjacent strip also reads. Default dispatch round-robins consecutive
// blocks across the 8 XCDs -> adjacent strips sit on different private L2s
// -> halo re-reads are HBM traffic. Remap so each XCD gets a contiguous
// chunk of (b, strip, half) blocks: adjacent strips run near-concurrently
// on the same XCD, reuse distance ~2 blocks x 30 KB << 4 MiB L2, so the
// halo becomes L2 hits. Predicted: kernel FETCH ~96 MB -> ~70 MB,
// kernel ~24.8 -> ~21 us.

constexpr int L  = 4000;
constexpr int D  = 512;
constexpr int SROWS   = 20;            // output rows per thread
constexpr int NSTRIPS = L / SROWS;     // 200

// optimal 9-comparator sorting network for 5, ascending
#define CE(a, b) { float lo_ = fminf(a, b); float hi_ = fmaxf(a, b); (a) = lo_; (b) = hi_; }

__global__ __launch_bounds__(256, 6)
void swd18_strip_scalar(const float* __restrict__ v, float* __restrict__ out) {
    // ---- T1: bijective XCD-chunk swizzle (m204 formula, nwg%8-safe) ----
    // Dispatch order linear id -> chunked id so XCD x owns a contiguous
    // run of (strip,half) blocks of one batch (for B=8: chunk == one b).
    const int nwg = gridDim.x * gridDim.y;
    const int lid = blockIdx.x + gridDim.x * blockIdx.y;   // dispatch order
    const int q   = nwg >> 3;
    const int rm  = nwg & 7;
    const int xcd = lid & 7;
    const int pos = lid >> 3;
    const int nid = (xcd < rm ? xcd * (q + 1) : rm * (q + 1) + (xcd - rm) * q) + pos;

    const int b     = nid / (NSTRIPS * 2);
    const int rr    = nid % (NSTRIPS * 2);
    const int half  = rr & 1;
    const int strip = rr >> 1;                     // 0..199; adjacent strips adjacent in nid
    const int i     = half * 256 + threadIdx.x;    // column 0..511

    const float* __restrict__ vb = v   + (size_t)b * (L * D);
    float*       __restrict__ ob = out + (size_t)b * (L * D);

    const int R0 = strip * SROWS;                  // multiple of 5

    // ---- 30 upfront loads: rows [R0-5, R0+25), cyclic only at the ends ----
    // Row index wave-uniform -> 64 lanes x 4B = 256B coalesced per instruction.
    float r[30];
    {
        int row = R0 - 5; if (row < 0) row += L;   // R0==0 wraps to L-5
#pragma unroll
        for (int j = 0; j < 5; ++j)
            r[j] = vb[(size_t)(row + j) * D + i];
    }
#pragma unroll
    for (int j = 5; j < 25; ++j)
        r[j] = vb[(size_t)(R0 + j - 5) * D + i];
    {
        int row = R0 + 20; if (row >= L) row -= L; // strip 199 wraps to 0
#pragma unroll
        for (int j = 25; j < 30; ++j)
            r[j] = vb[(size_t)(row + j - 25) * D + i];
    }

    const int rc = i % 5;
    const bool e0 = rc == 0, e1 = rc == 1, e2 = rc == 2, e3 = rc == 3;

    // ---- 4 groups; per group the verified R7 A/B window + output mux ----
#pragma unroll
    for (int k = 0; k < 4; ++k) {
        const float* p = &r[5 * k];                // pg = p[0..4], cu = p[5..9], ng = p[10..14]

        float A0 = e0 ? p[0] : e1 ? p[1] : e2 ? p[2] : e3 ? p[3] : p[4];
        float A1 = e0 ? p[1] : e1 ? p[2] : e2 ? p[3] : e3 ? p[4] : p[5];
        float A2 = e0 ? p[2] : e1 ? p[3] : e2 ? p[4] : e3 ? p[5] : p[6];
        float A3 = e0 ? p[3] : e1 ? p[4] : e2 ? p[5] : e3 ? p[6] : p[7];
        float A4 = e0 ? p[4] : e1 ? p[5] : e2 ? p[6] : e3 ? p[7] : p[8];
        float B0 = e0 ? p[5] : e1 ? p[6] : e2 ? p[7] : e3 ? p[8] : p[9];
        float B1 = e0 ? p[6] : e1 ? p[7] : e2 ? p[8] : e3 ? p[9] : p[10];
        float B2 = e0 ? p[7] : e1 ? p[8] : e2 ? p[9] : e3 ? p[10] : p[11];
        float B3 = e0 ? p[8] : e1 ? p[9] : e2 ? p[10] : e3 ? p[11] : p[12];
        float B4 = e0 ? p[9] : e1 ? p[10] : e2 ? p[11] : e3 ? p[12] : p[13];

        CE(A0, A1) CE(A3, A4) CE(A2, A4) CE(A2, A3) CE(A1, A4)
        CE(A0, A3) CE(A0, A2) CE(A1, A3) CE(A1, A2)
        CE(B0, B1) CE(B3, B4) CE(B2, B4) CE(B2, B3) CE(B1, B4)
        CE(B0, B3) CE(B0, B2) CE(B1, B3) CE(B1, B2)

        // out[R0+5k+t] = (t < rc) ? A[t+5-rc] : B[t-rc]
        float f0 = e0 ? B0 : e1 ? A4 : e2 ? A3 : e3 ? A2 : A1;
        float f1 = e0 ? B1 : e1 ? B0 : e2 ? A4 : e3 ? A3 : A2;
        float f2 = e0 ? B2 : e1 ? B1 : e2 ? B0 : e3 ? A4 : A3;
        float f3 = e0 ? B3 : e1 ? B2 : e2 ? B1 : e3 ? B0 : A4;
        float f4 = e0 ? B4 : e1 ? B3 : e2 ? B2 : e3 ? B1 : B0;

        float* o = ob + (size_t)(R0 + 5 * k) * D + i;   // rows never wrap
        __builtin_nontemporal_store(f0, o + 0 * D);
        __builtin_nontemporal_store(f1, o + 1 * D);
        __builtin_nontemporal_store(f2, o + 2 * D);
        __builtin_nontemporal_store(f3, o + 3 * D);
        __builtin_nontemporal_store(f4, o + 4 * D);
    }
}

#undef CE

extern "C" void kernel_launch(void* const* d_in, const int* in_sizes, int n_in,
                              void* d_out, int out_size, void* d_ws, size_t ws_size,
                              hipStream_t stream) {
    // setup_inputs order: q, k, v — only v is used by the reference forward.
    const float* v = (const float*)d_in[2];
    float* out = (float*)d_out;

    const int B = in_sizes[2] / (L * D);           // 8 for the bench shape
    dim3 grid(NSTRIPS * 2, B);                     // 400 x 8 = 3200 blocks of 256
    swd18_strip_scalar<<<grid, dim3(256), 0, stream>>>(v, out);
}